// Round 12
// baseline (2183.309 us; speedup 1.0000x reference)
//
#include <hip/hip_runtime.h>
#include <math.h>

#define NN 20000
#define NE 320000
#define NG 50

#define INV_SQRT8  0.35355339059327373f
#define INV_SQRT32 0.17677669529663687f
#define INV_SQRT96 0.10206207261596575f
#define INV_NN     0.25f
#define CS_        0.3826834323650898f
#define CX_        0.9238795325112867f
#define SQRT3_     1.7320508075688772f
#define INV_SQRT3  0.5773502691896258f
#define A_S_       0.013975424859373686f
#define A_V_       0.015625f
#define PI_        3.14159265358979323846f

typedef __attribute__((ext_vector_type(8))) short bf16x8;
typedef __attribute__((ext_vector_type(4))) float f32x4;

__device__ __forceinline__ float siluf(float x) { return x / (1.0f + expf(-x)); }
__device__ __forceinline__ float sigmf(float x) { return 1.0f / (1.0f + expf(-x)); }

// round-to-nearest-even bf16 split: x ~= hi + lo
__device__ __forceinline__ void bsplit(float x, unsigned short& h, unsigned short& l) {
  unsigned int u = __float_as_uint(x);
  unsigned short hh = (unsigned short)((u + 0x7FFFu + ((u>>16)&1u))>>16);
  float fh = __uint_as_float(((unsigned int)hh)<<16);
  float r = x - fh;
  unsigned int u2 = __float_as_uint(r);
  unsigned short ll = (unsigned short)((u2 + 0x7FFFu + ((u2>>16)&1u))>>16);
  h = hh; l = ll;
}

// ================= CSR build =================
__global__ __launch_bounds__(256) void k_hist(const int* __restrict__ edst, int* __restrict__ deg) {
  int e = blockIdx.x*256 + threadIdx.x;
  if (e < NE) atomicAdd(&deg[edst[e]], 1);
}

__global__ __launch_bounds__(256) void k_scan(const int* __restrict__ deg,
                                              int* __restrict__ rows, int* __restrict__ cursor) {
  __shared__ int buf[256];
  __shared__ int carry;
  int t = threadIdx.x;
  if (t == 0) { carry = 0; rows[0] = 0; }
  __syncthreads();
  for (int base = 0; base < NN; base += 256) {
    int i = base + t;
    int v = (i < NN) ? deg[i] : 0;
    buf[t] = v; __syncthreads();
    #pragma unroll
    for (int off = 1; off < 256; off <<= 1) {
      int x = (t >= off) ? buf[t-off] : 0;
      __syncthreads();
      buf[t] += x;
      __syncthreads();
    }
    int incl = buf[t] + carry;
    if (i < NN) { rows[i+1] = incl; cursor[i] = incl - v; }
    __syncthreads();
    if (t == 255) carry = incl;
    __syncthreads();
  }
}

__global__ __launch_bounds__(256) void k_scatter(const int* __restrict__ edst,
                                                 int* __restrict__ cursor, int* __restrict__ perm) {
  int e = blockIdx.x*256 + threadIdx.x;
  if (e >= NE) return;
  int p = atomicAdd(&cursor[edst[e]], 1);
  perm[p] = e;
}

// ================= geometry (sorted order) =================
__global__ __launch_bounds__(256) void k_geom(
    const float* __restrict__ pos, const int* __restrict__ esrc, const int* __restrict__ edst,
    const int* __restrict__ perm, int* __restrict__ esrc_s,
    float* __restrict__ ea_s, float* __restrict__ ea_v, float* __restrict__ basis) {
  int p = blockIdx.x*256 + threadIdx.x;
  if (p >= NE) return;
  int e = perm[p];
  int s = esrc[e], d = edst[e];
  esrc_s[p] = s;
  float vx = pos[3*s]   - pos[3*d];
  float vy = pos[3*s+1] - pos[3*d+1];
  float vz = pos[3*s+2] - pos[3*d+2];
  float r  = sqrtf(vx*vx + vy*vy + vz*vz + 1e-12f);
  float rs = fmaxf(r, 1e-6f);
  float inv = 1.0f / rs;
  float u = 2.0f*(r*(1.0f/3.5f) - 1.0f);
  float cut;
  if (u > 0.0f) cut = 0.0f;
  else if (u < -1.0f) cut = 1.0f;
  else cut = 0.5f*(1.0f - cosf(PI_*u));
  ea_s[p] = cut;
  float f = cut * SQRT3_ * inv;
  ea_v[p] = f*vx; ea_v[NE+p] = f*vy; ea_v[2*NE+p] = f*vz;
  const float cb = 2.1380899352993947f; // sqrt(2/3.5)*sqrt(8)
  #pragma unroll
  for (int n = 1; n <= 8; ++n)
    basis[(size_t)(n-1)*NE + p] = cb * sinf((float)n * (PI_/3.5f) * rs) * inv;
}

// ================= weight transpose (radial MLP layer-1 only) ==============
__global__ __launch_bounds__(256) void k_prep(
    const float* __restrict__ fc0_w1, const float* __restrict__ fc_w1,
    float* __restrict__ w1t) {
  int t = threadIdx.x;
  for (int idx = t; idx < 512; idx += 256) { int j = idx >> 3, k = idx & 7; w1t[idx] = fc0_w1[k*64 + j]; }
  for (int L = 0; L < 2; ++L)
    for (int idx = t; idx < 512; idx += 256) { int j = idx >> 3, k = idx & 7; w1t[512 + L*512 + idx] = fc_w1[L*512 + k*64 + j]; }
}

// ================= TP weight pack: fp32 -> fragment-ordered bf16 hi/lo ======
// dest idx = ((kt*NT + nt)*64 + lane)*8 + e ; k = kt*32+(lane>>4)*8+e ; n = nt*16+(lane&15)
__global__ __launch_bounds__(256) void k_packw(
    const float* __restrict__ srcA, const float* __restrict__ srcB,
    unsigned short* __restrict__ dh, unsigned short* __restrict__ dl,
    int K, int N, int bound, float scA, float scB) {
  int idx = blockIdx.x*256 + threadIdx.x;
  if (idx >= K*N) return;
  int e = idx & 7;
  int lane = (idx >> 3) & 63;
  int rest = idx >> 9;
  int NT = N >> 4;
  int nt = rest % NT;
  int kt = rest / NT;
  int k = kt*32 + (lane>>4)*8 + e;
  int n = nt*16 + (lane&15);
  float w;
  if (k < bound) w = srcA[(size_t)k*N + n]*scA;
  else           w = srcB[(size_t)(k-bound)*N + n]*scB;
  unsigned short h, l;
  bsplit(w, h, l);
  dh[idx] = h; dl[idx] = l;
}

// ================= node embed + layer0 linears =================
__global__ __launch_bounds__(256) void k_node0(
    const int* __restrict__ atype, const float* __restrict__ embed,
    const float* __restrict__ w_tp0, const float* __restrict__ sc0, const float* __restrict__ lin1_0,
    float* __restrict__ SC, float* __restrict__ LSB0) {
  int n = blockIdx.x*256 + threadIdx.x;
  if (n >= NN) return;
  int at = atype[n];
  float x[8];
  #pragma unroll
  for (int i = 0; i < 8; ++i) x[i] = embed[at*8 + i];
  float tc[8] = {0,0,0,0,0,0,0,0};
  #pragma unroll
  for (int i = 0; i < 8; ++i)
    #pragma unroll
    for (int j = 0; j < 8; ++j) {
      float p = x[i]*x[j];
      #pragma unroll
      for (int k = 0; k < 8; ++k) tc[k] += p * w_tp0[(i*8+j)*8 + k];
    }
  #pragma unroll
  for (int k = 0; k < 8; ++k) tc[k] *= 0.125f;
  #pragma unroll 1
  for (int k = 0; k < 96; ++k) {
    float a = 0.f;
    #pragma unroll
    for (int i = 0; i < 8; ++i) a += tc[i]*sc0[i*96+k];
    SC[(size_t)k*NN + n] = a * INV_SQRT8;
  }
  #pragma unroll
  for (int u = 0; u < 8; ++u) {
    float a = 0.f;
    #pragma unroll
    for (int i = 0; i < 8; ++i) a += tc[i]*lin1_0[i*8+u];
    LSB0[(size_t)n*8 + u] = a * INV_SQRT8;   // node-major
  }
}

// ================= radial kernels ==========================================
// j-loop FULLY unrolled (static idx -> h[] stays in VGPRs, rule #20).
// Channel chunks split over blockIdx.y (4 blocks x 3 chunks): 4x wave
// parallelism to hide s_load/barrier latency; h recomputed per y-block
// (bitwise identical, +12% MAC). Stores staged through LDS for full lines.
__global__ __launch_bounds__(256) void k_radial0(
    const float* __restrict__ BAS, const float* __restrict__ EAS,
    const float* __restrict__ w1t, const float* __restrict__ w2,   // w2 = fc0_w2 [64][16]
    float* __restrict__ RW, int pLo, int pHi, int cap) {
  __shared__ float tile[256*17];
  int t = threadIdx.x;
  int idx = blockIdx.x*256 + t;
  int p = pLo + idx;
  bool alive = p < pHi;
  float h[64];
  float es = 0.f;
  if (alive) {
    float b[8];
    #pragma unroll
    for (int k = 0; k < 8; ++k) b[k] = BAS[(size_t)k*NE + p];
    #pragma unroll
    for (int j = 0; j < 64; ++j) {
      float a = 0.f;
      #pragma unroll
      for (int k = 0; k < 8; ++k) a += b[k]*w1t[j*8+k];
      h[j] = siluf(a * INV_SQRT8);
    }
    es = EAS[p];
  }
  if (alive) {
    float acc[16] = {};
    #pragma unroll
    for (int j = 0; j < 64; ++j) {
      float hj = h[j];
      #pragma unroll
      for (int c = 0; c < 16; ++c) acc[c] += hj * w2[j*16 + c];
    }
    #pragma unroll
    for (int c = 0; c < 16; ++c) {
      float a = acc[c] * 0.125f;
      if (c < 8) a *= es;
      tile[t*17 + c] = a;
    }
  }
  __syncthreads();
  int e0 = blockIdx.x*256;
  #pragma unroll
  for (int i = 0; i < 16; ++i) {
    int lin = i*256 + t;
    int e = lin >> 4, c = lin & 15;
    if (pLo + e0 + e < pHi)
      RW[(size_t)(e0 + e)*16 + c] = tile[e*17 + c];
  }
}

__global__ __launch_bounds__(256) void k_radial(
    const float* __restrict__ BAS, const float* __restrict__ EAS,
    const float* __restrict__ w1t, const float* __restrict__ w2,   // w2 = fc_w2+L*12288 [64][192]
    float* __restrict__ RW, int pLo, int pHi, int cap) {
  __shared__ float tile[256*17];
  int t = threadIdx.x;
  int idx = blockIdx.x*256 + t;
  int p = pLo + idx;
  bool alive = p < pHi;
  float h[64];
  float es = 0.f;
  if (alive) {
    float b[8];
    #pragma unroll
    for (int k = 0; k < 8; ++k) b[k] = BAS[(size_t)k*NE + p];
    #pragma unroll
    for (int j = 0; j < 64; ++j) {
      float a = 0.f;
      #pragma unroll
      for (int k = 0; k < 8; ++k) a += b[k]*w1t[j*8+k];
      h[j] = siluf(a * INV_SQRT8);
    }
    es = EAS[p];
  }
  int e0 = blockIdx.x*256;
  int cc0 = blockIdx.y*3;          // 4 y-blocks x 3 chunks = 12 chunks
  #pragma unroll 1
  for (int ci = 0; ci < 3; ++ci) {
    int cc = cc0 + ci;
    if (alive) {
      float acc[16] = {};
      #pragma unroll
      for (int j = 0; j < 64; ++j) {
        float hj = h[j];
        const float* wr = w2 + j*192 + cc*16;
        #pragma unroll
        for (int c = 0; c < 16; ++c) acc[c] += hj * wr[c];
      }
      #pragma unroll
      for (int c = 0; c < 16; ++c) {
        int ch = cc*16 + c;
        float a = acc[c] * 0.125f;
        float f = (ch < 64) ? es : ((ch < 128) ? 1.0f : ((ch < 160) ? es : INV_SQRT3));
        tile[t*17 + c] = a*f;
      }
    }
    __syncthreads();
    #pragma unroll
    for (int i = 0; i < 16; ++i) {
      int lin = i*256 + t;
      int e = lin >> 4, c = lin & 15;
      if (pLo + e0 + e < pHi)
        RW[(size_t)(e0 + e)*192 + cc*16 + c] = tile[e*17 + c];
    }
    __syncthreads();
  }
}

// ================= gather kernels (wave per dst, NO atomics) =================
__global__ __launch_bounds__(256) void k_gather0(
    const int* __restrict__ rows, const int* __restrict__ esrc_s,
    const float* __restrict__ EAV, const float* __restrict__ RW,
    const float* __restrict__ LSB0, float* __restrict__ AG0,
    int pLo, int pHi, int cap) {
  int t = blockIdx.x*256 + threadIdx.x;     // t < NN*8
  int d = t >> 3, u = t & 7;
  int lo = rows[d], hi = rows[d+1];
  lo = lo > pLo ? lo : pLo;
  hi = hi < pHi ? hi : pHi;
  if (lo >= hi) return;
  float aS = 0.f, a0 = 0.f, a1 = 0.f, a2 = 0.f;
  for (int p = lo; p < hi; ++p) {
    int q = p - pLo;
    int sn = esrc_s[p];
    float xe = LSB0[(size_t)sn*8 + u];
    const float* rwp = RW + (size_t)q*16;
    float r0 = rwp[u];        // w[:8]*es folded
    float r1 = rwp[8+u];      // w[8:16]
    aS += r0*xe;
    float tt = r1*xe;
    a0 += tt*EAV[p]; a1 += tt*EAV[NE+p]; a2 += tt*EAV[2*NE+p];
  }
  float* ag = AG0 + (size_t)d*32;
  ag[u] += aS;
  ag[8 + u*3 + 0] += a0;
  ag[8 + u*3 + 1] += a1;
  ag[8 + u*3 + 2] += a2;
}

__global__ __launch_bounds__(256) void k_gather(
    const int* __restrict__ rows, const int* __restrict__ esrc_s,
    const float* __restrict__ EAS, const float* __restrict__ EAV,
    const float* __restrict__ RW, const float* __restrict__ LSB, const float* __restrict__ LVB,
    float* __restrict__ AG, int pLo, int pHi, int cap) {
  int gw = (blockIdx.x*256 + threadIdx.x) >> 6;   // wave id = dst node
  int lane = threadIdx.x & 63;
  if (gw >= NN) return;
  int lo = rows[gw], hi = rows[gw+1];
  lo = lo > pLo ? lo : pLo;
  hi = hi < pHi ? hi : pHi;
  if (lo >= hi) return;
  int k = lane & 31;
  bool low = lane < 32;
  float aS=0.f, aV0=0.f, aV1=0.f, aV2=0.f, aS2=0.f, aW0=0.f, aW1=0.f, aW2=0.f;
  for (int p = lo; p < hi; ++p) {
    int q = p - pLo;
    int sn = esrc_s[p];
    float ev0 = EAV[p], ev1 = EAV[NE+p], ev2 = EAV[2*NE+p];
    float se = LSB[(size_t)sn*64 + lane];
    const float* rwp = RW + (size_t)q*192;
    float r0 = rwp[lane];       // w0*es
    float r1 = rwp[64+lane];    // w1
    aS += r0*se;
    float t = r1*se;
    aV0 += t*ev0; aV1 += t*ev1; aV2 += t*ev2;
    if (low) {
      float ve0 = LVB[(size_t)sn*96 + k*3 + 0];
      float ve1 = LVB[(size_t)sn*96 + k*3 + 1];
      float ve2 = LVB[(size_t)sn*96 + k*3 + 2];
      float r2 = rwp[128+k];    // w2*es
      float r3 = rwp[160+k];    // w3/sqrt3
      aS2 += r3*(ve0*ev0 + ve1*ev1 + ve2*ev2);
      aW0 += r2*ve0; aW1 += r2*ve1; aW2 += r2*ve2;
    }
  }
  float* ag = AG + (size_t)gw*384;
  ag[lane] += aS;
  ag[96 + lane*3 + 0] += aV0;
  ag[96 + lane*3 + 1] += aV1;
  ag[96 + lane*3 + 2] += aV2;
  if (low) {
    ag[64 + k] += aS2;
    ag[96 + (64+k)*3 + 0] += aW0;
    ag[96 + (64+k)*3 + 1] += aW1;
    ag[96 + (64+k)*3 + 2] += aW2;
  }
}

// ================= layer0 node update =================
__global__ __launch_bounds__(256) void k_upd0(
    const float* __restrict__ lin2_0s, const float* __restrict__ lin2_0v,
    float* __restrict__ SC, float* __restrict__ SCV,
    const float* __restrict__ AG0,
    float* __restrict__ SB, float* __restrict__ VB) {
  int n = blockIdx.x*256 + threadIdx.x;
  if (n >= NN) return;
  float as[8], av[24];
  #pragma unroll
  for (int u = 0; u < 8; ++u) as[u] = AG0[(size_t)n*32 + u] * INV_NN;
  #pragma unroll
  for (int u = 0; u < 24; ++u) av[u] = AG0[(size_t)n*32 + 8 + u] * INV_NN;
  float ssum = 0.f;
  #pragma unroll 1
  for (int k = 0; k < 96; ++k) {
    float a = 0.f;
    #pragma unroll
    for (int u = 0; u < 8; ++u) a += as[u]*lin2_0s[u*96+k];
    float y = CS_*SC[(size_t)k*NN+n] + CX_*INV_SQRT8*a;
    SC[(size_t)k*NN+n] = y; ssum += y*y;
  }
  float vsum = 0.f;
  #pragma unroll 1
  for (int k = 0; k < 32; ++k) {
    #pragma unroll
    for (int c = 0; c < 3; ++c) {
      float a = 0.f;
      #pragma unroll
      for (int u = 0; u < 8; ++u) a += av[u*3+c]*lin2_0v[u*32+k];
      float y = a * INV_SQRT8;  // no C_S/C_X on vector path in layer 0
      SCV[(size_t)(k*3+c)*NN+n] = y; vsum += y*y;
    }
  }
  float sinv = rsqrtf(ssum*(1.0f/96.0f) + 1e-6f);
  float vinv = rsqrtf(vsum*(1.0f/32.0f) + 1e-6f);
  #pragma unroll 1
  for (int k = 0; k < 64; ++k) {
    float y = SC[(size_t)k*NN+n]*sinv;
    SB[(size_t)k*NN+n] = siluf(y);
  }
  #pragma unroll
  for (int k = 0; k < 32; ++k) {
    float g = sigmf(SC[(size_t)(64+k)*NN+n]*sinv) * vinv;
    #pragma unroll
    for (int c = 0; c < 3; ++c)
      VB[(size_t)(k*3+c)*NN+n] = g * SCV[(size_t)(k*3+c)*NN+n];
  }
}

// ================= per-layer node linears (sc, lin1) =================
__global__ __launch_bounds__(256) void k_pre(
    const float* __restrict__ scsW, const float* __restrict__ scvW,
    const float* __restrict__ l1sW, const float* __restrict__ l1vW,
    const float* __restrict__ SB, const float* __restrict__ VB,
    float* __restrict__ SC, float* __restrict__ SCV,
    float* __restrict__ LSB, float* __restrict__ LVB) {
  int n = blockIdx.x*256 + threadIdx.x;
  if (n >= NN) return;
  float s[64];
  #pragma unroll
  for (int u = 0; u < 64; ++u) s[u] = SB[(size_t)u*NN + n];
  #pragma unroll 1
  for (int k = 0; k < 96; ++k) {
    float a = 0.f;
    #pragma unroll
    for (int u = 0; u < 64; ++u) a += s[u]*scsW[u*96+k];
    SC[(size_t)k*NN+n] = a * 0.125f;
  }
  #pragma unroll 1
  for (int k = 0; k < 64; ++k) {
    float a = 0.f;
    #pragma unroll
    for (int u = 0; u < 64; ++u) a += s[u]*l1sW[u*64+k];
    LSB[(size_t)n*64 + k] = a * 0.125f;      // node-major for gather
  }
  for (int c = 0; c < 3; ++c) {
    float v[32];
    #pragma unroll
    for (int u = 0; u < 32; ++u) v[u] = VB[(size_t)(u*3+c)*NN + n];
    #pragma unroll 1
    for (int k = 0; k < 32; ++k) {
      float a = 0.f;
      #pragma unroll
      for (int u = 0; u < 32; ++u) a += v[u]*scvW[u*32+k];
      SCV[(size_t)(k*3+c)*NN+n] = a * INV_SQRT32;
    }
    #pragma unroll 1
    for (int k = 0; k < 32; ++k) {
      float a = 0.f;
      #pragma unroll
      for (int u = 0; u < 32; ++u) a += v[u]*l1vW[u*32+k];
      LVB[(size_t)n*96 + k*3 + c] = a * INV_SQRT32;   // node-major for gather
    }
  }
}

// ================= per-layer node update =================
__global__ __launch_bounds__(256) void k_upd(
    const float* __restrict__ l2sW, const float* __restrict__ l2vW,
    float* __restrict__ SC, float* __restrict__ SCV,
    const float* __restrict__ AG) {
  int n = blockIdx.x*256 + threadIdx.x;
  if (n >= NN) return;
  float ssum = 0.f;
  {
    float ag[96];
    #pragma unroll
    for (int u = 0; u < 96; ++u) ag[u] = AG[(size_t)n*384 + u] * INV_NN;
    #pragma unroll 1
    for (int k = 0; k < 96; ++k) {
      float a = 0.f;
      #pragma unroll
      for (int u = 0; u < 96; ++u) a += ag[u]*l2sW[u*96+k];
      float y = CS_*SC[(size_t)k*NN+n] + CX_*INV_SQRT96*a;
      SC[(size_t)k*NN+n] = y; ssum += y*y;
    }
  }
  float vsum = 0.f;
  for (int c = 0; c < 3; ++c) {
    float ag[96];
    #pragma unroll
    for (int u = 0; u < 96; ++u) ag[u] = AG[(size_t)n*384 + 96 + u*3 + c] * INV_NN;
    #pragma unroll 1
    for (int k = 0; k < 32; ++k) {
      float a = 0.f;
      #pragma unroll
      for (int u = 0; u < 96; ++u) a += ag[u]*l2vW[u*32+k];
      float y = CS_*SCV[(size_t)(k*3+c)*NN+n] + CX_*INV_SQRT96*a;
      SCV[(size_t)(k*3+c)*NN+n] = y; vsum += y*y;
    }
  }
  float sinv = rsqrtf(ssum*(1.0f/96.0f) + 1e-6f);
  float vinv = rsqrtf(vsum*(1.0f/32.0f) + 1e-6f);
  #pragma unroll 1
  for (int k = 0; k < 64; ++k) {
    float y = SC[(size_t)k*NN+n]*sinv;
    SC[(size_t)k*NN+n] = siluf(y);
  }
  #pragma unroll
  for (int k = 0; k < 32; ++k) {
    float g = sigmf(SC[(size_t)(64+k)*NN+n]*sinv) * vinv;
    #pragma unroll
    for (int c = 0; c < 3; ++c)
      SCV[(size_t)(k*3+c)*NN+n] *= g;
  }
}

// ================= MFMA tensor-product GEMM ==================================
// OUT[n, :] (+)= P[n, :K] @ W[K, N], P built on the fly from per-node s/v.
// MODE 0: out_s  K=5120 (4096 ss + 1024 vv), N=64, DST=SB (+=)
// MODE 1: out_v  K=4096 (2048 sv + 2048 vs), N=32, c=blockIdx.y, DST=VB (+=)
// MODE 2: pen    K=5120, N=16, S=SB V=VB, DST=X16 (=)
template<int MODE>
__global__ __launch_bounds__(256) void k_tpg(
    const unsigned short* __restrict__ WH, const unsigned short* __restrict__ WL,
    const float* __restrict__ S, const float* __restrict__ V,
    float* __restrict__ DST) {
  constexpr int K   = (MODE==1) ? 4096 : 5120;
  constexpr int NT  = (MODE==0) ? 4 : ((MODE==1) ? 2 : 1);
  constexpr int BND = (MODE==1) ? 2048 : 4096;
  constexpr int NSTEP = K/32;
  __shared__ float s_lds[32][68];                      // padded: stride 68
  __shared__ float v_lds[(MODE==1)?1:3][32][36];       // padded: stride 36
  __shared__ unsigned short ph[2][64][8];              // [msub][fraglane][e] contiguous
  __shared__ unsigned short pl[2][64][8];
  int t = threadIdx.x;
  int nb = blockIdx.x*32;
  int c  = (MODE==1) ? blockIdx.y : 0;
  // ---- stage s/v tiles ----
  for (int idx = t; idx < 32*64; idx += 256) {
    int m = idx & 31, ch = idx >> 5;
    s_lds[m][ch] = S[(size_t)ch*NN + nb + m];
  }
  if (MODE == 1) {
    for (int idx = t; idx < 32*32; idx += 256) {
      int m = idx & 31, kch = idx >> 5;
      v_lds[0][m][kch] = V[(size_t)(kch*3 + c)*NN + nb + m];
    }
  } else {
    for (int idx = t; idx < 32*96; idx += 256) {
      int m = idx & 31, rest = idx >> 5;     // rest = kch*3 + cc
      int cc = rest % 3, kch = rest / 3;
      v_lds[cc][m][kch] = V[(size_t)rest*NN + nb + m];
    }
  }
  __syncthreads();
  int wv = t >> 6, lane = t & 63;
  // builder mapping: thread -> (msub, frag lane, half of 8 k's)
  int bms   = t >> 7;              // 0..1
  int bu    = t & 127;
  int bfl   = bu >> 1;             // frag lane 0..63
  int bhalf = bu & 1;              // which 4 of the 8 k's
  int bm    = bms*16 + (bfl&15);
  int bkl   = (bfl>>4)*8 + bhalf*4;
  int my_nt = (MODE==0) ? wv : ((MODE==1) ? (wv&1) : 0);
  f32x4 accA = {0.f,0.f,0.f,0.f};
  f32x4 accB = {0.f,0.f,0.f,0.f};
  for (int kt = 0; kt < NSTEP; ++kt) {
    // B fragments (coalesced 16B/lane, L2-resident) — issue before build
    size_t boff = (((size_t)kt*NT + my_nt)*64 + lane)*8;
    bf16x8 bh = *reinterpret_cast<const bf16x8*>(WH + boff);
    bf16x8 bl = *reinterpret_cast<const bf16x8*>(WL + boff);
    // ---- build P slice (4 entries/thread) ----
    int k0 = kt*32 + bkl;
    float p0, p1, p2, p3;
    if (MODE != 1) {
      if (k0 < BND) {
        int i = k0 >> 6, j0 = k0 & 63;
        float si = s_lds[bm][i];
        p0 = si*s_lds[bm][j0+0]; p1 = si*s_lds[bm][j0+1];
        p2 = si*s_lds[bm][j0+2]; p3 = si*s_lds[bm][j0+3];
      } else {
        int kk = k0 - BND;
        int i = kk >> 5, j0 = kk & 31;
        float a0 = v_lds[0][bm][i], a1 = v_lds[1][bm][i], a2 = v_lds[2][bm][i];
        p0 = a0*v_lds[0][bm][j0+0] + a1*v_lds[1][bm][j0+0] + a2*v_lds[2][bm][j0+0];
        p1 = a0*v_lds[0][bm][j0+1] + a1*v_lds[1][bm][j0+1] + a2*v_lds[2][bm][j0+1];
        p2 = a0*v_lds[0][bm][j0+2] + a1*v_lds[1][bm][j0+2] + a2*v_lds[2][bm][j0+2];
        p3 = a0*v_lds[0][bm][j0+3] + a1*v_lds[1][bm][j0+3] + a2*v_lds[2][bm][j0+3];
      }
    } else {
      if (k0 < BND) {
        int i = k0 >> 5, j0 = k0 & 31;
        float si = s_lds[bm][i];
        p0 = si*v_lds[0][bm][j0+0]; p1 = si*v_lds[0][bm][j0+1];
        p2 = si*v_lds[0][bm][j0+2]; p3 = si*v_lds[0][bm][j0+3];
      } else {
        int kk = k0 - BND;
        int i = kk >> 6, j0 = kk & 63;
        float vi = v_lds[0][bm][i];
        p0 = vi*s_lds[bm][j0+0]; p1 = vi*s_lds[bm][j0+1];
        p2 = vi*s_lds[bm][j0+2]; p3 = vi*s_lds[bm][j0+3];
      }
    }
    ushort4 hh, ll;
    bsplit(p0, hh.x, ll.x); bsplit(p1, hh.y, ll.y);
    bsplit(p2, hh.z, ll.z); bsplit(p3, hh.w, ll.w);
    *reinterpret_cast<ushort4*>(&ph[bms][bfl][bhalf*4]) = hh;
    *reinterpret_cast<ushort4*>(&pl[bms][bfl][bhalf*4]) = ll;
    __syncthreads();
    // ---- MFMA ----
    if (MODE == 0) {
      bf16x8 a0h = *reinterpret_cast<const bf16x8*>(&ph[0][lane][0]);
      bf16x8 a0l = *reinterpret_cast<const bf16x8*>(&pl[0][lane][0]);
      bf16x8 a1h = *reinterpret_cast<const bf16x8*>(&ph[1][lane][0]);
      bf16x8 a1l = *reinterpret_cast<const bf16x8*>(&pl[1][lane][0]);
      accA = __builtin_amdgcn_mfma_f32_16x16x32_bf16(a0h, bh, accA, 0, 0, 0);
      accA = __builtin_amdgcn_mfma_f32_16x16x32_bf16(a0h, bl, accA, 0, 0, 0);
      accA = __builtin_amdgcn_mfma_f32_16x16x32_bf16(a0l, bh, accA, 0, 0, 0);
      accB = __builtin_amdgcn_mfma_f32_16x16x32_bf16(a1h, bh, accB, 0, 0, 0);
      accB = __builtin_amdgcn_mfma_f32_16x16x32_bf16(a1h, bl, accB, 0, 0, 0);
      accB = __builtin_amdgcn_mfma_f32_16x16x32_bf16(a1l, bh, accB, 0, 0, 0);
    } else if (MODE == 1) {
      int ms = wv >> 1;
      bf16x8 ah = *reinterpret_cast<const bf16x8*>(&ph[ms][lane][0]);
      bf16x8 al = *reinterpret_cast<const bf16x8*>(&pl[ms][lane][0]);
      accA = __builtin_amdgcn_mfma_f32_16x16x32_bf16(ah, bh, accA, 0, 0, 0);
      accA = __builtin_amdgcn_mfma_f32_16x16x32_bf16(ah, bl, accA, 0, 0, 0);
      accA = __builtin_amdgcn_mfma_f32_16x16x32_bf16(al, bh, accA, 0, 0, 0);
    } else {
      if (wv < 2) {
        bf16x8 ah = *reinterpret_cast<const bf16x8*>(&ph[wv][lane][0]);
        bf16x8 al = *reinterpret_cast<const bf16x8*>(&pl[wv][lane][0]);
        accA = __builtin_amdgcn_mfma_f32_16x16x32_bf16(ah, bh, accA, 0, 0, 0);
        accA = __builtin_amdgcn_mfma_f32_16x16x32_bf16(ah, bl, accA, 0, 0, 0);
        accA = __builtin_amdgcn_mfma_f32_16x16x32_bf16(al, bh, accA, 0, 0, 0);
      }
    }
    __syncthreads();
  }
  // ---- epilogue: C/D layout col=lane&15, row=(lane>>4)*4+reg ----
  int col = lane & 15;
  int rb  = (lane >> 4) * 4;
  if (MODE == 0) {
    #pragma unroll
    for (int r = 0; r < 4; ++r) {
      int node = nb + rb + r;
      int ch = wv*16 + col;
      DST[(size_t)ch*NN + node]      += accA[r];
      DST[(size_t)ch*NN + node + 16] += accB[r];
    }
  } else if (MODE == 1) {
    int ms = wv >> 1, ntl = wv & 1;
    #pragma unroll
    for (int r = 0; r < 4; ++r) {
      int node = nb + ms*16 + rb + r;
      int ch = ntl*16 + col;
      DST[(size_t)(ch*3 + c)*NN + node] += accA[r];
    }
  } else {
    if (wv < 2) {
      #pragma unroll
      for (int r = 0; r < 4; ++r) {
        int node = nb + wv*16 + rb + r;
        DST[(size_t)col*NN + node] = accA[r];
      }
    }
  }
}

// ================= final bilinear + LDS-binned graph pool =================
__global__ __launch_bounds__(256) void k_fin2(
    const float* __restrict__ wl, const int* __restrict__ batch,
    const float* __restrict__ X16, float* __restrict__ out) {
  __shared__ float bins[NG];
  int t = threadIdx.x;
  for (int i = t; i < NG; i += 256) bins[i] = 0.f;
  __syncthreads();
  int n = blockIdx.x*256 + t;
  if (n < NN) {
    float x16[16];
    #pragma unroll
    for (int k = 0; k < 16; ++k) x16[k] = siluf(X16[(size_t)k*NN + n]);
    float o = 0.f;
    #pragma unroll
    for (int i = 0; i < 16; ++i) {
      float xi = x16[i];
      #pragma unroll
      for (int j = 0; j < 16; ++j) o += xi*x16[j]*wl[i*16+j];
    }
    o *= (1.0f/16.0f)*0.05f;  // /16 then /sqrt(400)
    atomicAdd(&bins[batch[n]], o);
  }
  __syncthreads();
  for (int i = t; i < NG; i += 256)
    if (bins[i] != 0.f) atomicAdd(&out[i], bins[i]);
}

extern "C" void kernel_launch(void* const* d_in, const int* in_sizes, int n_in,
                              void* d_out, int out_size, void* d_ws, size_t ws_size,
                              hipStream_t stream) {
  const float* pos     = (const float*)d_in[0];
  const int*   atype   = (const int*)d_in[1];
  const int*   esrc    = (const int*)d_in[2];
  const int*   edst    = (const int*)d_in[3];
  const int*   batch   = (const int*)d_in[4];
  const float* embed   = (const float*)d_in[5];
  const float* w_tp0   = (const float*)d_in[6];
  const float* tpss    = (const float*)d_in[7];
  const float* tpvv    = (const float*)d_in[8];
  const float* tpsv    = (const float*)d_in[9];
  const float* tpvs    = (const float*)d_in[10];
  const float* pen_ss  = (const float*)d_in[11];
  const float* pen_vv  = (const float*)d_in[12];
  const float* w_last  = (const float*)d_in[13];
  const float* sc0     = (const float*)d_in[14];
  const float* lin1_0  = (const float*)d_in[15];
  const float* fc0_w1  = (const float*)d_in[16];
  const float* fc0_w2  = (const float*)d_in[17];
  const float* lin2_0s = (const float*)d_in[18];
  const float* lin2_0v = (const float*)d_in[19];
  const float* sc_s    = (const float*)d_in[20];
  const float* sc_v    = (const float*)d_in[21];
  const float* lin1_s  = (const float*)d_in[22];
  const float* lin1_v  = (const float*)d_in[23];
  const float* fc_w1   = (const float*)d_in[24];
  const float* fc_w2   = (const float*)d_in[25];
  const float* lin2_s  = (const float*)d_in[26];
  const float* lin2_v  = (const float*)d_in[27];

  float* ws = (float*)d_ws;
  float* out = (float*)d_out;

  size_t o = 0;
  float* EA_S = ws + o; o += NE;
  float* EA_V = ws + o; o += 3*(size_t)NE;
  float* BAS  = ws + o; o += 8*(size_t)NE;
  float* W1T  = ws + o; o += 1536;
  float* SC   = ws + o; o += 96*(size_t)NN;
  float* SCV  = ws + o; o += 96*(size_t)NN;
  float* LSB  = ws + o; o += 64*(size_t)NN;   // node-major; layer0 uses first 8*NN as [n][8]
  float* LVB  = ws + o; o += 96*(size_t)NN;   // node-major
  float* AG   = ws + o; o += 384*(size_t)NN;  // node-major
  float* AG0  = ws + o; o += 32*(size_t)NN;   // node-major
  float* SB   = ws + o; o += 64*(size_t)NN;
  float* VB   = ws + o; o += 96*(size_t)NN;
  float* X16  = ws + o; o += 16*(size_t)NN;
  int* ESRC_S = (int*)(ws + o); o += NE;
  int* PERM   = (int*)(ws + o); o += NE;
  int* DEG    = (int*)(ws + o); o += NN;
  int* ROWS   = (int*)(ws + o); o += NN + 1;
  int* CURSOR = (int*)(ws + o); o += NN;
  // packed TP weights (bf16 hi/lo, fragment order)
  unsigned short* PWS = (unsigned short*)(ws + o); o += 999424;  // 1,998,848 ushorts
  unsigned short* WSh[2] = { PWS,            PWS + 655360 };
  unsigned short* WSl[2] = { PWS + 327680,   PWS + 983040 };
  unsigned short* WVh[2] = { PWS + 1310720,  PWS + 1572864 };
  unsigned short* WVl[2] = { PWS + 1441792,  PWS + 1703936 };
  unsigned short* WPh    =   PWS + 1835008;
  unsigned short* WPl    =   PWS + 1916928;
  float* RW   = ws + o;

  size_t availF = (ws_size/4 > o) ? (ws_size/4 - o) : 0;
  size_t capL = (availF/192) & ~(size_t)255;
  int cap  = (int)(capL < (size_t)NE ? capL : (size_t)NE);
  if (cap < 1024) cap = 1024;
  size_t cap0L = (availF/16) & ~(size_t)255;
  int cap0 = (int)(cap0L < (size_t)NE ? cap0L : (size_t)NE);
  if (cap0 < 1024) cap0 = 1024;

  const int nbE = NE/256;        // 1250
  const int nbN = (NN+255)/256;  // 79
  const int nbG = NN*64/256;     // 5000 (wave per dst)
  const int nbG0 = NN*8/256;     // 625
  const int nbM = NN/32;         // 625 (mfma node tiles)

  hipMemsetAsync(out, 0, NG*sizeof(float), stream);
  // ---- CSR (once per call, shared by all 3 conv layers) ----
  hipMemsetAsync(DEG, 0, NN*sizeof(int), stream);
  k_hist<<<nbE,256,0,stream>>>(edst, DEG);
  k_scan<<<1,256,0,stream>>>(DEG, ROWS, CURSOR);
  k_scatter<<<nbE,256,0,stream>>>(edst, CURSOR, PERM);
  k_geom<<<nbE,256,0,stream>>>(pos, esrc, edst, PERM, ESRC_S, EA_S, EA_V, BAS);
  k_prep<<<1,256,0,stream>>>(fc0_w1, fc_w1, W1T);
  // ---- pack TP weights (scales folded) ----
  for (int L = 0; L < 2; ++L) {
    k_packw<<<1280,256,0,stream>>>(tpss + (size_t)L*262144, tpvv + (size_t)L*65536,
                                   WSh[L], WSl[L], 5120, 64, 4096,
                                   0.1f*A_S_, 0.1f*A_S_*INV_SQRT3);
    k_packw<<<512,256,0,stream>>>(tpsv + (size_t)L*65536, tpvs + (size_t)L*65536,
                                  WVh[L], WVl[L], 4096, 32, 2048,
                                  0.1f*A_V_, 0.1f*A_V_);
  }
  k_packw<<<320,256,0,stream>>>(pen_ss, pen_vv, WPh, WPl, 5120, 16, 4096,
                                A_S_, A_S_*INV_SQRT3);
  k_node0<<<nbN,256,0,stream>>>(atype, embed, w_tp0, sc0, lin1_0, SC, LSB);

  // ---- layer 0 conv ----
  hipMemsetAsync(AG0, 0, 32*(size_t)NN*sizeof(float), stream);
  for (int pLo = 0; pLo < NE; pLo += cap0) {
    int pHi = pLo + cap0 < NE ? pLo + cap0 : NE;
    int nb = (pHi - pLo + 255)/256;
    k_radial0<<<nb,256,0,stream>>>(BAS, EA_S, W1T, fc0_w2, RW, pLo, pHi, cap0);
    k_gather0<<<nbG0,256,0,stream>>>(ROWS, ESRC_S, EA_V, RW, LSB, AG0, pLo, pHi, cap0);
  }
  k_upd0<<<nbN,256,0,stream>>>(lin2_0s, lin2_0v, SC, SCV, AG0, SB, VB);

  // ---- layers 1,2 ----
  for (int L = 0; L < 2; ++L) {
    k_pre<<<nbN,256,0,stream>>>(sc_s + L*64*96, sc_v + L*32*32,
                                lin1_s + L*64*64, lin1_v + L*32*32,
                                SB, VB, SC, SCV, LSB, LVB);
    hipMemsetAsync(AG, 0, 384*(size_t)NN*sizeof(float), stream);
    for (int pLo = 0; pLo < NE; pLo += cap) {
      int pHi = pLo + cap < NE ? pLo + cap : NE;
      int nb = (pHi - pLo + 255)/256;
      k_radial<<<dim3(nb,4),256,0,stream>>>(BAS, EA_S, W1T + 512 + L*512, fc_w2 + (size_t)L*12288, RW, pLo, pHi, cap);
      k_gather<<<nbG,256,0,stream>>>(ROWS, ESRC_S, EA_S, EA_V, RW, LSB, LVB, AG, pLo, pHi, cap);
    }
    k_upd<<<nbN,256,0,stream>>>(lin2_s + L*96*96, lin2_v + L*96*32, SC, SCV, AG);
    // MFMA self tensor product (residual)
    k_tpg<0><<<nbM,256,0,stream>>>(WSh[L], WSl[L], SC, SCV, SB);
    k_tpg<1><<<dim3(nbM,3),256,0,stream>>>(WVh[L], WVl[L], SC, SCV, VB);
  }
  k_tpg<2><<<nbM,256,0,stream>>>(WPh, WPl, SB, VB, X16);
  k_fin2<<<nbN,256,0,stream>>>(w_last, batch, X16, out);
}

// Round 13
// 1801.387 us; speedup vs baseline: 1.2120x; 1.2120x over previous
//
#include <hip/hip_runtime.h>
#include <math.h>

#define NN 20000
#define NE 320000
#define NG 50

#define INV_SQRT8  0.35355339059327373f
#define INV_SQRT32 0.17677669529663687f
#define INV_SQRT96 0.10206207261596575f
#define INV_NN     0.25f
#define CS_        0.3826834323650898f
#define CX_        0.9238795325112867f
#define SQRT3_     1.7320508075688772f
#define INV_SQRT3  0.5773502691896258f
#define A_S_       0.013975424859373686f
#define A_V_       0.015625f
#define PI_        3.14159265358979323846f

typedef __attribute__((ext_vector_type(8))) short bf16x8;
typedef __attribute__((ext_vector_type(4))) float f32x4;

__device__ __forceinline__ float siluf(float x) { return x / (1.0f + expf(-x)); }
__device__ __forceinline__ float sigmf(float x) { return 1.0f / (1.0f + expf(-x)); }

// round-to-nearest-even bf16 split: x ~= hi + lo
__device__ __forceinline__ void bsplit(float x, unsigned short& h, unsigned short& l) {
  unsigned int u = __float_as_uint(x);
  unsigned short hh = (unsigned short)((u + 0x7FFFu + ((u>>16)&1u))>>16);
  float fh = __uint_as_float(((unsigned int)hh)<<16);
  float r = x - fh;
  unsigned int u2 = __float_as_uint(r);
  unsigned short ll = (unsigned short)((u2 + 0x7FFFu + ((u2>>16)&1u))>>16);
  h = hh; l = ll;
}

// ================= CSR build =================
__global__ __launch_bounds__(256) void k_hist(const int* __restrict__ edst, int* __restrict__ deg) {
  int e = blockIdx.x*256 + threadIdx.x;
  if (e < NE) atomicAdd(&deg[edst[e]], 1);
}

__global__ __launch_bounds__(256) void k_scan(const int* __restrict__ deg,
                                              int* __restrict__ rows, int* __restrict__ cursor) {
  __shared__ int buf[256];
  __shared__ int carry;
  int t = threadIdx.x;
  if (t == 0) { carry = 0; rows[0] = 0; }
  __syncthreads();
  for (int base = 0; base < NN; base += 256) {
    int i = base + t;
    int v = (i < NN) ? deg[i] : 0;
    buf[t] = v; __syncthreads();
    #pragma unroll
    for (int off = 1; off < 256; off <<= 1) {
      int x = (t >= off) ? buf[t-off] : 0;
      __syncthreads();
      buf[t] += x;
      __syncthreads();
    }
    int incl = buf[t] + carry;
    if (i < NN) { rows[i+1] = incl; cursor[i] = incl - v; }
    __syncthreads();
    if (t == 255) carry = incl;
    __syncthreads();
  }
}

__global__ __launch_bounds__(256) void k_scatter(const int* __restrict__ edst,
                                                 int* __restrict__ cursor, int* __restrict__ perm) {
  int e = blockIdx.x*256 + threadIdx.x;
  if (e >= NE) return;
  int p = atomicAdd(&cursor[edst[e]], 1);
  perm[p] = e;
}

// ================= geometry (sorted order) =================
__global__ __launch_bounds__(256) void k_geom(
    const float* __restrict__ pos, const int* __restrict__ esrc, const int* __restrict__ edst,
    const int* __restrict__ perm, int* __restrict__ esrc_s,
    float* __restrict__ ea_s, float* __restrict__ ea_v, float* __restrict__ basis) {
  int p = blockIdx.x*256 + threadIdx.x;
  if (p >= NE) return;
  int e = perm[p];
  int s = esrc[e], d = edst[e];
  esrc_s[p] = s;
  float vx = pos[3*s]   - pos[3*d];
  float vy = pos[3*s+1] - pos[3*d+1];
  float vz = pos[3*s+2] - pos[3*d+2];
  float r  = sqrtf(vx*vx + vy*vy + vz*vz + 1e-12f);
  float rs = fmaxf(r, 1e-6f);
  float inv = 1.0f / rs;
  float u = 2.0f*(r*(1.0f/3.5f) - 1.0f);
  float cut;
  if (u > 0.0f) cut = 0.0f;
  else if (u < -1.0f) cut = 1.0f;
  else cut = 0.5f*(1.0f - cosf(PI_*u));
  ea_s[p] = cut;
  float f = cut * SQRT3_ * inv;
  ea_v[p] = f*vx; ea_v[NE+p] = f*vy; ea_v[2*NE+p] = f*vz;
  const float cb = 2.1380899352993947f; // sqrt(2/3.5)*sqrt(8)
  #pragma unroll
  for (int n = 1; n <= 8; ++n)
    basis[(size_t)(n-1)*NE + p] = cb * sinf((float)n * (PI_/3.5f) * rs) * inv;
}

// ================= weight transpose (radial MLP layer-1 only) ==============
__global__ __launch_bounds__(256) void k_prep(
    const float* __restrict__ fc0_w1, const float* __restrict__ fc_w1,
    float* __restrict__ w1t) {
  int t = threadIdx.x;
  for (int idx = t; idx < 512; idx += 256) { int j = idx >> 3, k = idx & 7; w1t[idx] = fc0_w1[k*64 + j]; }
  for (int L = 0; L < 2; ++L)
    for (int idx = t; idx < 512; idx += 256) { int j = idx >> 3, k = idx & 7; w1t[512 + L*512 + idx] = fc_w1[L*512 + k*64 + j]; }
}

// ================= TP weight pack: fp32 -> fragment-ordered bf16 hi/lo ======
__global__ __launch_bounds__(256) void k_packw(
    const float* __restrict__ srcA, const float* __restrict__ srcB,
    unsigned short* __restrict__ dh, unsigned short* __restrict__ dl,
    int K, int N, int bound, float scA, float scB) {
  int idx = blockIdx.x*256 + threadIdx.x;
  if (idx >= K*N) return;
  int e = idx & 7;
  int lane = (idx >> 3) & 63;
  int rest = idx >> 9;
  int NT = N >> 4;
  int nt = rest % NT;
  int kt = rest / NT;
  int k = kt*32 + (lane>>4)*8 + e;
  int n = nt*16 + (lane&15);
  float w;
  if (k < bound) w = srcA[(size_t)k*N + n]*scA;
  else           w = srcB[(size_t)(k-bound)*N + n]*scB;
  unsigned short h, l;
  bsplit(w, h, l);
  dh[idx] = h; dl[idx] = l;
}

// ================= radial MLP2 weight pack (K=64, N=192) ===================
// folds 0.125 and the ch>=160 1/sqrt3; es applied at runtime in epilogue.
__global__ __launch_bounds__(256) void k_packr(
    const float* __restrict__ src,  // [64][192]
    unsigned short* __restrict__ dh, unsigned short* __restrict__ dl) {
  int idx = blockIdx.x*256 + threadIdx.x;
  if (idx >= 12288) return;
  int e = idx & 7;
  int lane = (idx >> 3) & 63;
  int rest = idx >> 9;            // 0..23
  int nt = rest % 12, kt = rest / 12;
  int k = kt*32 + (lane>>4)*8 + e;
  int n = nt*16 + (lane&15);
  float w = src[k*192 + n] * 0.125f;
  if (n >= 160) w *= INV_SQRT3;
  unsigned short h, l; bsplit(w, h, l);
  dh[idx] = h; dl[idx] = l;
}

// ================= node embed + layer0 linears =================
__global__ __launch_bounds__(256) void k_node0(
    const int* __restrict__ atype, const float* __restrict__ embed,
    const float* __restrict__ w_tp0, const float* __restrict__ sc0, const float* __restrict__ lin1_0,
    float* __restrict__ SC, float* __restrict__ LSB0) {
  int n = blockIdx.x*256 + threadIdx.x;
  if (n >= NN) return;
  int at = atype[n];
  float x[8];
  #pragma unroll
  for (int i = 0; i < 8; ++i) x[i] = embed[at*8 + i];
  float tc[8] = {0,0,0,0,0,0,0,0};
  #pragma unroll
  for (int i = 0; i < 8; ++i)
    #pragma unroll
    for (int j = 0; j < 8; ++j) {
      float p = x[i]*x[j];
      #pragma unroll
      for (int k = 0; k < 8; ++k) tc[k] += p * w_tp0[(i*8+j)*8 + k];
    }
  #pragma unroll
  for (int k = 0; k < 8; ++k) tc[k] *= 0.125f;
  #pragma unroll 1
  for (int k = 0; k < 96; ++k) {
    float a = 0.f;
    #pragma unroll
    for (int i = 0; i < 8; ++i) a += tc[i]*sc0[i*96+k];
    SC[(size_t)k*NN + n] = a * INV_SQRT8;
  }
  #pragma unroll
  for (int u = 0; u < 8; ++u) {
    float a = 0.f;
    #pragma unroll
    for (int i = 0; i < 8; ++i) a += tc[i]*lin1_0[i*8+u];
    LSB0[(size_t)n*8 + u] = a * INV_SQRT8;   // node-major
  }
}

// ================= layer-0 radial (16 ch, VALU path) ========================
__global__ __launch_bounds__(256) void k_radial0(
    const float* __restrict__ BAS, const float* __restrict__ EAS,
    const float* __restrict__ w1t, const float* __restrict__ w2,   // w2 = fc0_w2 [64][16]
    float* __restrict__ RW, int pLo, int pHi, int cap) {
  __shared__ float tile[256*17];
  int t = threadIdx.x;
  int idx = blockIdx.x*256 + t;
  int p = pLo + idx;
  bool alive = p < pHi;
  float h[64];
  float es = 0.f;
  if (alive) {
    float b[8];
    #pragma unroll
    for (int k = 0; k < 8; ++k) b[k] = BAS[(size_t)k*NE + p];
    #pragma unroll
    for (int j = 0; j < 64; ++j) {
      float a = 0.f;
      #pragma unroll
      for (int k = 0; k < 8; ++k) a += b[k]*w1t[j*8+k];
      h[j] = siluf(a * INV_SQRT8);
    }
    es = EAS[p];
  }
  if (alive) {
    float acc[16] = {};
    #pragma unroll
    for (int j = 0; j < 64; ++j) {
      float hj = h[j];
      #pragma unroll
      for (int c = 0; c < 16; ++c) acc[c] += hj * w2[j*16 + c];
    }
    #pragma unroll
    for (int c = 0; c < 16; ++c) {
      float a = acc[c] * 0.125f;
      if (c < 8) a *= es;
      tile[t*17 + c] = a;
    }
  }
  __syncthreads();
  int e0 = blockIdx.x*256;
  #pragma unroll
  for (int i = 0; i < 16; ++i) {
    int lin = i*256 + t;
    int e = lin >> 4, c = lin & 15;
    if (pLo + e0 + e < pHi)
      RW[(size_t)(e0 + e)*16 + c] = tile[e*17 + c];
  }
}

// ================= layers 1,2 radial: MFMA GEMM =============================
// RW[32-edge tile][192] = silu-H[32][64] @ W2frag[64][192]; hi/lo bf16 split.
__global__ __launch_bounds__(256) void k_radialg(
    const float* __restrict__ BAS, const float* __restrict__ EAS,
    const float* __restrict__ w1t,
    const unsigned short* __restrict__ WH, const unsigned short* __restrict__ WL,
    float* __restrict__ RW, int pLo, int pHi, int cap) {
  __shared__ float bas_lds[32][9];
  __shared__ float es_lds[32];
  __shared__ unsigned short ph[2][2][64][8];  // [kt][ms][fraglane][e] contiguous
  __shared__ unsigned short pl[2][2][64][8];
  int t = threadIdx.x;
  int e0 = blockIdx.x*32;
  // stage basis + cutoff for 32 edges
  for (int idx = t; idx < 32*8; idx += 256) {
    int m = idx >> 3, k = idx & 7;
    int p = pLo + e0 + m;
    bas_lds[m][k] = (p < pHi) ? BAS[(size_t)k*NE + p] : 0.f;
  }
  if (t < 32) {
    int p = pLo + e0 + t;
    es_lds[t] = (p < pHi) ? EAS[p] : 0.f;
  }
  __syncthreads();
  // build A fragments: thread -> (ms, fraglane, half), 4 j's per kt, both kt
  int bms = t >> 7, bu = t & 127, bfl = bu >> 1, bhalf = bu & 1;
  int bm = bms*16 + (bfl & 15);
  int jb = (bfl >> 4)*8 + bhalf*4;
  float b0=bas_lds[bm][0],b1=bas_lds[bm][1],b2=bas_lds[bm][2],b3=bas_lds[bm][3];
  float b4=bas_lds[bm][4],b5=bas_lds[bm][5],b6=bas_lds[bm][6],b7=bas_lds[bm][7];
  #pragma unroll
  for (int kt = 0; kt < 2; ++kt) {
    ushort4 hh, ll;
    #pragma unroll
    for (int q = 0; q < 4; ++q) {
      int j = kt*32 + jb + q;
      const float* wr = w1t + j*8;
      float a = b0*wr[0]+b1*wr[1]+b2*wr[2]+b3*wr[3]+b4*wr[4]+b5*wr[5]+b6*wr[6]+b7*wr[7];
      float hv = siluf(a * INV_SQRT8);
      unsigned short hq, lq; bsplit(hv, hq, lq);
      ((unsigned short*)&hh)[q] = hq; ((unsigned short*)&ll)[q] = lq;
    }
    *reinterpret_cast<ushort4*>(&ph[kt][bms][bfl][bhalf*4]) = hh;
    *reinterpret_cast<ushort4*>(&pl[kt][bms][bfl][bhalf*4]) = ll;
  }
  __syncthreads();
  int wv = t >> 6, lane = t & 63;
  f32x4 accA0 = {0.f,0.f,0.f,0.f}, accA1 = {0.f,0.f,0.f,0.f}, accA2 = {0.f,0.f,0.f,0.f};
  f32x4 accB0 = {0.f,0.f,0.f,0.f}, accB1 = {0.f,0.f,0.f,0.f}, accB2 = {0.f,0.f,0.f,0.f};
  #pragma unroll
  for (int kt = 0; kt < 2; ++kt) {
    bf16x8 a0h = *reinterpret_cast<const bf16x8*>(&ph[kt][0][lane][0]);
    bf16x8 a0l = *reinterpret_cast<const bf16x8*>(&pl[kt][0][lane][0]);
    bf16x8 a1h = *reinterpret_cast<const bf16x8*>(&ph[kt][1][lane][0]);
    bf16x8 a1l = *reinterpret_cast<const bf16x8*>(&pl[kt][1][lane][0]);
    #pragma unroll
    for (int ci = 0; ci < 3; ++ci) {
      int nt = wv*3 + ci;
      size_t boff = (((size_t)kt*12 + nt)*64 + lane)*8;
      bf16x8 bh = *reinterpret_cast<const bf16x8*>(WH + boff);
      bf16x8 bl = *reinterpret_cast<const bf16x8*>(WL + boff);
      f32x4 aA = (ci==0)?accA0:((ci==1)?accA1:accA2);
      f32x4 aB = (ci==0)?accB0:((ci==1)?accB1:accB2);
      aA = __builtin_amdgcn_mfma_f32_16x16x32_bf16(a0h, bh, aA, 0,0,0);
      aA = __builtin_amdgcn_mfma_f32_16x16x32_bf16(a0h, bl, aA, 0,0,0);
      aA = __builtin_amdgcn_mfma_f32_16x16x32_bf16(a0l, bh, aA, 0,0,0);
      aB = __builtin_amdgcn_mfma_f32_16x16x32_bf16(a1h, bh, aB, 0,0,0);
      aB = __builtin_amdgcn_mfma_f32_16x16x32_bf16(a1h, bl, aB, 0,0,0);
      aB = __builtin_amdgcn_mfma_f32_16x16x32_bf16(a1l, bh, aB, 0,0,0);
      if (ci==0) { accA0 = aA; accB0 = aB; }
      else if (ci==1) { accA1 = aA; accB1 = aB; }
      else { accA2 = aA; accB2 = aB; }
    }
  }
  // epilogue: C/D col=lane&15, row=(lane>>4)*4+reg; 64B-contiguous per 16 lanes
  int col = lane & 15, rb = (lane>>4)*4;
  #pragma unroll
  for (int ci = 0; ci < 3; ++ci) {
    int ch = (wv*3+ci)*16 + col;
    bool esf = (ch < 64) || (ch >= 128 && ch < 160);
    f32x4 aA = (ci==0)?accA0:((ci==1)?accA1:accA2);
    f32x4 aB = (ci==0)?accB0:((ci==1)?accB1:accB2);
    #pragma unroll
    for (int r = 0; r < 4; ++r) {
      int m0 = rb + r;
      if (pLo + e0 + m0 < pHi) {
        float v = aA[r];
        if (esf) v *= es_lds[m0];
        RW[(size_t)(e0 + m0)*192 + ch] = v;
      }
      int m1 = 16 + rb + r;
      if (pLo + e0 + m1 < pHi) {
        float v = aB[r];
        if (esf) v *= es_lds[m1];
        RW[(size_t)(e0 + m1)*192 + ch] = v;
      }
    }
  }
}

// ================= gather kernels (wave per dst, NO atomics) =================
__global__ __launch_bounds__(256) void k_gather0(
    const int* __restrict__ rows, const int* __restrict__ esrc_s,
    const float* __restrict__ EAV, const float* __restrict__ RW,
    const float* __restrict__ LSB0, float* __restrict__ AG0,
    int pLo, int pHi, int cap) {
  int t = blockIdx.x*256 + threadIdx.x;     // t < NN*8
  int d = t >> 3, u = t & 7;
  int lo = rows[d], hi = rows[d+1];
  lo = lo > pLo ? lo : pLo;
  hi = hi < pHi ? hi : pHi;
  if (lo >= hi) return;
  float aS = 0.f, a0 = 0.f, a1 = 0.f, a2 = 0.f;
  for (int p = lo; p < hi; ++p) {
    int q = p - pLo;
    int sn = esrc_s[p];
    float xe = LSB0[(size_t)sn*8 + u];
    const float* rwp = RW + (size_t)q*16;
    float r0 = rwp[u];        // w[:8]*es folded
    float r1 = rwp[8+u];      // w[8:16]
    aS += r0*xe;
    float tt = r1*xe;
    a0 += tt*EAV[p]; a1 += tt*EAV[NE+p]; a2 += tt*EAV[2*NE+p];
  }
  float* ag = AG0 + (size_t)d*32;
  ag[u] += aS;
  ag[8 + u*3 + 0] += a0;
  ag[8 + u*3 + 1] += a1;
  ag[8 + u*3 + 2] += a2;
}

__global__ __launch_bounds__(256) void k_gather(
    const int* __restrict__ rows, const int* __restrict__ esrc_s,
    const float* __restrict__ EAS, const float* __restrict__ EAV,
    const float* __restrict__ RW, const float* __restrict__ LSB, const float* __restrict__ LVB,
    float* __restrict__ AG, int pLo, int pHi, int cap) {
  int gw = (blockIdx.x*256 + threadIdx.x) >> 6;   // wave id = dst node
  int lane = threadIdx.x & 63;
  if (gw >= NN) return;
  int lo = rows[gw], hi = rows[gw+1];
  lo = lo > pLo ? lo : pLo;
  hi = hi < pHi ? hi : pHi;
  if (lo >= hi) return;
  int k = lane & 31;
  bool low = lane < 32;
  float aS=0.f, aV0=0.f, aV1=0.f, aV2=0.f, aS2=0.f, aW0=0.f, aW1=0.f, aW2=0.f;
  for (int p = lo; p < hi; ++p) {
    int q = p - pLo;
    int sn = esrc_s[p];
    float ev0 = EAV[p], ev1 = EAV[NE+p], ev2 = EAV[2*NE+p];
    float se = LSB[(size_t)sn*64 + lane];
    const float* rwp = RW + (size_t)q*192;
    float r0 = rwp[lane];       // w0*es
    float r1 = rwp[64+lane];    // w1
    aS += r0*se;
    float t = r1*se;
    aV0 += t*ev0; aV1 += t*ev1; aV2 += t*ev2;
    if (low) {
      float ve0 = LVB[(size_t)sn*96 + k*3 + 0];
      float ve1 = LVB[(size_t)sn*96 + k*3 + 1];
      float ve2 = LVB[(size_t)sn*96 + k*3 + 2];
      float r2 = rwp[128+k];    // w2*es
      float r3 = rwp[160+k];    // w3/sqrt3
      aS2 += r3*(ve0*ev0 + ve1*ev1 + ve2*ev2);
      aW0 += r2*ve0; aW1 += r2*ve1; aW2 += r2*ve2;
    }
  }
  float* ag = AG + (size_t)gw*384;
  ag[lane] += aS;
  ag[96 + lane*3 + 0] += aV0;
  ag[96 + lane*3 + 1] += aV1;
  ag[96 + lane*3 + 2] += aV2;
  if (low) {
    ag[64 + k] += aS2;
    ag[96 + (64+k)*3 + 0] += aW0;
    ag[96 + (64+k)*3 + 1] += aW1;
    ag[96 + (64+k)*3 + 2] += aW2;
  }
}

// ================= layer0 node update =================
__global__ __launch_bounds__(256) void k_upd0(
    const float* __restrict__ lin2_0s, const float* __restrict__ lin2_0v,
    float* __restrict__ SC, float* __restrict__ SCV,
    const float* __restrict__ AG0,
    float* __restrict__ SB, float* __restrict__ VB) {
  int n = blockIdx.x*256 + threadIdx.x;
  if (n >= NN) return;
  float as[8], av[24];
  #pragma unroll
  for (int u = 0; u < 8; ++u) as[u] = AG0[(size_t)n*32 + u] * INV_NN;
  #pragma unroll
  for (int u = 0; u < 24; ++u) av[u] = AG0[(size_t)n*32 + 8 + u] * INV_NN;
  float ssum = 0.f;
  #pragma unroll 1
  for (int k = 0; k < 96; ++k) {
    float a = 0.f;
    #pragma unroll
    for (int u = 0; u < 8; ++u) a += as[u]*lin2_0s[u*96+k];
    float y = CS_*SC[(size_t)k*NN+n] + CX_*INV_SQRT8*a;
    SC[(size_t)k*NN+n] = y; ssum += y*y;
  }
  float vsum = 0.f;
  #pragma unroll 1
  for (int k = 0; k < 32; ++k) {
    #pragma unroll
    for (int c = 0; c < 3; ++c) {
      float a = 0.f;
      #pragma unroll
      for (int u = 0; u < 8; ++u) a += av[u*3+c]*lin2_0v[u*32+k];
      float y = a * INV_SQRT8;  // no C_S/C_X on vector path in layer 0
      SCV[(size_t)(k*3+c)*NN+n] = y; vsum += y*y;
    }
  }
  float sinv = rsqrtf(ssum*(1.0f/96.0f) + 1e-6f);
  float vinv = rsqrtf(vsum*(1.0f/32.0f) + 1e-6f);
  #pragma unroll 1
  for (int k = 0; k < 64; ++k) {
    float y = SC[(size_t)k*NN+n]*sinv;
    SB[(size_t)k*NN+n] = siluf(y);
  }
  #pragma unroll
  for (int k = 0; k < 32; ++k) {
    float g = sigmf(SC[(size_t)(64+k)*NN+n]*sinv) * vinv;
    #pragma unroll
    for (int c = 0; c < 3; ++c)
      VB[(size_t)(k*3+c)*NN+n] = g * SCV[(size_t)(k*3+c)*NN+n];
  }
}

// ================= per-layer node linears (sc, lin1) =================
__global__ __launch_bounds__(256) void k_pre(
    const float* __restrict__ scsW, const float* __restrict__ scvW,
    const float* __restrict__ l1sW, const float* __restrict__ l1vW,
    const float* __restrict__ SB, const float* __restrict__ VB,
    float* __restrict__ SC, float* __restrict__ SCV,
    float* __restrict__ LSB, float* __restrict__ LVB) {
  int n = blockIdx.x*256 + threadIdx.x;
  if (n >= NN) return;
  float s[64];
  #pragma unroll
  for (int u = 0; u < 64; ++u) s[u] = SB[(size_t)u*NN + n];
  #pragma unroll 1
  for (int k = 0; k < 96; ++k) {
    float a = 0.f;
    #pragma unroll
    for (int u = 0; u < 64; ++u) a += s[u]*scsW[u*96+k];
    SC[(size_t)k*NN+n] = a * 0.125f;
  }
  #pragma unroll 1
  for (int k = 0; k < 64; ++k) {
    float a = 0.f;
    #pragma unroll
    for (int u = 0; u < 64; ++u) a += s[u]*l1sW[u*64+k];
    LSB[(size_t)n*64 + k] = a * 0.125f;      // node-major for gather
  }
  for (int c = 0; c < 3; ++c) {
    float v[32];
    #pragma unroll
    for (int u = 0; u < 32; ++u) v[u] = VB[(size_t)(u*3+c)*NN + n];
    #pragma unroll 1
    for (int k = 0; k < 32; ++k) {
      float a = 0.f;
      #pragma unroll
      for (int u = 0; u < 32; ++u) a += v[u]*scvW[u*32+k];
      SCV[(size_t)(k*3+c)*NN+n] = a * INV_SQRT32;
    }
    #pragma unroll 1
    for (int k = 0; k < 32; ++k) {
      float a = 0.f;
      #pragma unroll
      for (int u = 0; u < 32; ++u) a += v[u]*l1vW[u*32+k];
      LVB[(size_t)n*96 + k*3 + c] = a * INV_SQRT32;   // node-major for gather
    }
  }
}

// ================= per-layer node update =================
__global__ __launch_bounds__(256) void k_upd(
    const float* __restrict__ l2sW, const float* __restrict__ l2vW,
    float* __restrict__ SC, float* __restrict__ SCV,
    const float* __restrict__ AG) {
  int n = blockIdx.x*256 + threadIdx.x;
  if (n >= NN) return;
  float ssum = 0.f;
  {
    float ag[96];
    #pragma unroll
    for (int u = 0; u < 96; ++u) ag[u] = AG[(size_t)n*384 + u] * INV_NN;
    #pragma unroll 1
    for (int k = 0; k < 96; ++k) {
      float a = 0.f;
      #pragma unroll
      for (int u = 0; u < 96; ++u) a += ag[u]*l2sW[u*96+k];
      float y = CS_*SC[(size_t)k*NN+n] + CX_*INV_SQRT96*a;
      SC[(size_t)k*NN+n] = y; ssum += y*y;
    }
  }
  float vsum = 0.f;
  for (int c = 0; c < 3; ++c) {
    float ag[96];
    #pragma unroll
    for (int u = 0; u < 96; ++u) ag[u] = AG[(size_t)n*384 + 96 + u*3 + c] * INV_NN;
    #pragma unroll 1
    for (int k = 0; k < 32; ++k) {
      float a = 0.f;
      #pragma unroll
      for (int u = 0; u < 96; ++u) a += ag[u]*l2vW[u*32+k];
      float y = CS_*SCV[(size_t)(k*3+c)*NN+n] + CX_*INV_SQRT96*a;
      SCV[(size_t)(k*3+c)*NN+n] = y; vsum += y*y;
    }
  }
  float sinv = rsqrtf(ssum*(1.0f/96.0f) + 1e-6f);
  float vinv = rsqrtf(vsum*(1.0f/32.0f) + 1e-6f);
  #pragma unroll 1
  for (int k = 0; k < 64; ++k) {
    float y = SC[(size_t)k*NN+n]*sinv;
    SC[(size_t)k*NN+n] = siluf(y);
  }
  #pragma unroll
  for (int k = 0; k < 32; ++k) {
    float g = sigmf(SC[(size_t)(64+k)*NN+n]*sinv) * vinv;
    #pragma unroll
    for (int c = 0; c < 3; ++c)
      SCV[(size_t)(k*3+c)*NN+n] *= g;
  }
}

// ================= MFMA tensor-product GEMM ==================================
// OUT[n, :] (+)= P[n, :K] @ W[K, N], P built on the fly from per-node s/v.
// MODE 0: out_s  K=5120 (4096 ss + 1024 vv), N=64, DST=SB (+=)
// MODE 1: out_v  K=4096 (2048 sv + 2048 vs), N=32, c=blockIdx.y, DST=VB (+=)
// MODE 2: pen    K=5120, N=16, S=SB V=VB, DST=X16 (=)
template<int MODE>
__global__ __launch_bounds__(256) void k_tpg(
    const unsigned short* __restrict__ WH, const unsigned short* __restrict__ WL,
    const float* __restrict__ S, const float* __restrict__ V,
    float* __restrict__ DST) {
  constexpr int K   = (MODE==1) ? 4096 : 5120;
  constexpr int NT  = (MODE==0) ? 4 : ((MODE==1) ? 2 : 1);
  constexpr int BND = (MODE==1) ? 2048 : 4096;
  constexpr int NSTEP = K/32;
  __shared__ float s_lds[32][68];                      // padded: stride 68
  __shared__ float v_lds[(MODE==1)?1:3][32][36];       // padded: stride 36
  __shared__ unsigned short ph[2][64][8];              // [msub][fraglane][e] contiguous
  __shared__ unsigned short pl[2][64][8];
  int t = threadIdx.x;
  int nb = blockIdx.x*32;
  int c  = (MODE==1) ? blockIdx.y : 0;
  // ---- stage s/v tiles ----
  for (int idx = t; idx < 32*64; idx += 256) {
    int m = idx & 31, ch = idx >> 5;
    s_lds[m][ch] = S[(size_t)ch*NN + nb + m];
  }
  if (MODE == 1) {
    for (int idx = t; idx < 32*32; idx += 256) {
      int m = idx & 31, kch = idx >> 5;
      v_lds[0][m][kch] = V[(size_t)(kch*3 + c)*NN + nb + m];
    }
  } else {
    for (int idx = t; idx < 32*96; idx += 256) {
      int m = idx & 31, rest = idx >> 5;     // rest = kch*3 + cc
      int cc = rest % 3, kch = rest / 3;
      v_lds[cc][m][kch] = V[(size_t)rest*NN + nb + m];
    }
  }
  __syncthreads();
  int wv = t >> 6, lane = t & 63;
  // builder mapping: thread -> (msub, frag lane, half of 8 k's)
  int bms   = t >> 7;              // 0..1
  int bu    = t & 127;
  int bfl   = bu >> 1;             // frag lane 0..63
  int bhalf = bu & 1;              // which 4 of the 8 k's
  int bm    = bms*16 + (bfl&15);
  int bkl   = (bfl>>4)*8 + bhalf*4;
  int my_nt = (MODE==0) ? wv : ((MODE==1) ? (wv&1) : 0);
  f32x4 accA = {0.f,0.f,0.f,0.f};
  f32x4 accB = {0.f,0.f,0.f,0.f};
  for (int kt = 0; kt < NSTEP; ++kt) {
    // B fragments (coalesced 16B/lane, L2-resident) — issue before build
    size_t boff = (((size_t)kt*NT + my_nt)*64 + lane)*8;
    bf16x8 bh = *reinterpret_cast<const bf16x8*>(WH + boff);
    bf16x8 bl = *reinterpret_cast<const bf16x8*>(WL + boff);
    // ---- build P slice (4 entries/thread) ----
    int k0 = kt*32 + bkl;
    float p0, p1, p2, p3;
    if (MODE != 1) {
      if (k0 < BND) {
        int i = k0 >> 6, j0 = k0 & 63;
        float si = s_lds[bm][i];
        p0 = si*s_lds[bm][j0+0]; p1 = si*s_lds[bm][j0+1];
        p2 = si*s_lds[bm][j0+2]; p3 = si*s_lds[bm][j0+3];
      } else {
        int kk = k0 - BND;
        int i = kk >> 5, j0 = kk & 31;
        float a0 = v_lds[0][bm][i], a1 = v_lds[1][bm][i], a2 = v_lds[2][bm][i];
        p0 = a0*v_lds[0][bm][j0+0] + a1*v_lds[1][bm][j0+0] + a2*v_lds[2][bm][j0+0];
        p1 = a0*v_lds[0][bm][j0+1] + a1*v_lds[1][bm][j0+1] + a2*v_lds[2][bm][j0+1];
        p2 = a0*v_lds[0][bm][j0+2] + a1*v_lds[1][bm][j0+2] + a2*v_lds[2][bm][j0+2];
        p3 = a0*v_lds[0][bm][j0+3] + a1*v_lds[1][bm][j0+3] + a2*v_lds[2][bm][j0+3];
      }
    } else {
      if (k0 < BND) {
        int i = k0 >> 5, j0 = k0 & 31;
        float si = s_lds[bm][i];
        p0 = si*v_lds[0][bm][j0+0]; p1 = si*v_lds[0][bm][j0+1];
        p2 = si*v_lds[0][bm][j0+2]; p3 = si*v_lds[0][bm][j0+3];
      } else {
        int kk = k0 - BND;
        int i = kk >> 6, j0 = kk & 63;
        float vi = v_lds[0][bm][i];
        p0 = vi*s_lds[bm][j0+0]; p1 = vi*s_lds[bm][j0+1];
        p2 = vi*s_lds[bm][j0+2]; p3 = vi*s_lds[bm][j0+3];
      }
    }
    ushort4 hh, ll;
    bsplit(p0, hh.x, ll.x); bsplit(p1, hh.y, ll.y);
    bsplit(p2, hh.z, ll.z); bsplit(p3, hh.w, ll.w);
    *reinterpret_cast<ushort4*>(&ph[bms][bfl][bhalf*4]) = hh;
    *reinterpret_cast<ushort4*>(&pl[bms][bfl][bhalf*4]) = ll;
    __syncthreads();
    // ---- MFMA ----
    if (MODE == 0) {
      bf16x8 a0h = *reinterpret_cast<const bf16x8*>(&ph[0][lane][0]);
      bf16x8 a0l = *reinterpret_cast<const bf16x8*>(&pl[0][lane][0]);
      bf16x8 a1h = *reinterpret_cast<const bf16x8*>(&ph[1][lane][0]);
      bf16x8 a1l = *reinterpret_cast<const bf16x8*>(&pl[1][lane][0]);
      accA = __builtin_amdgcn_mfma_f32_16x16x32_bf16(a0h, bh, accA, 0, 0, 0);
      accA = __builtin_amdgcn_mfma_f32_16x16x32_bf16(a0h, bl, accA, 0, 0, 0);
      accA = __builtin_amdgcn_mfma_f32_16x16x32_bf16(a0l, bh, accA, 0, 0, 0);
      accB = __builtin_amdgcn_mfma_f32_16x16x32_bf16(a1h, bh, accB, 0, 0, 0);
      accB = __builtin_amdgcn_mfma_f32_16x16x32_bf16(a1h, bl, accB, 0, 0, 0);
      accB = __builtin_amdgcn_mfma_f32_16x16x32_bf16(a1l, bh, accB, 0, 0, 0);
    } else if (MODE == 1) {
      int ms = wv >> 1;
      bf16x8 ah = *reinterpret_cast<const bf16x8*>(&ph[ms][lane][0]);
      bf16x8 al = *reinterpret_cast<const bf16x8*>(&pl[ms][lane][0]);
      accA = __builtin_amdgcn_mfma_f32_16x16x32_bf16(ah, bh, accA, 0, 0, 0);
      accA = __builtin_amdgcn_mfma_f32_16x16x32_bf16(ah, bl, accA, 0, 0, 0);
      accA = __builtin_amdgcn_mfma_f32_16x16x32_bf16(al, bh, accA, 0, 0, 0);
    } else {
      if (wv < 2) {
        bf16x8 ah = *reinterpret_cast<const bf16x8*>(&ph[wv][lane][0]);
        bf16x8 al = *reinterpret_cast<const bf16x8*>(&pl[wv][lane][0]);
        accA = __builtin_amdgcn_mfma_f32_16x16x32_bf16(ah, bh, accA, 0, 0, 0);
        accA = __builtin_amdgcn_mfma_f32_16x16x32_bf16(ah, bl, accA, 0, 0, 0);
        accA = __builtin_amdgcn_mfma_f32_16x16x32_bf16(al, bh, accA, 0, 0, 0);
      }
    }
    __syncthreads();
  }
  // ---- epilogue: C/D layout col=lane&15, row=(lane>>4)*4+reg ----
  int col = lane & 15;
  int rb  = (lane >> 4) * 4;
  if (MODE == 0) {
    #pragma unroll
    for (int r = 0; r < 4; ++r) {
      int node = nb + rb + r;
      int ch = wv*16 + col;
      DST[(size_t)ch*NN + node]      += accA[r];
      DST[(size_t)ch*NN + node + 16] += accB[r];
    }
  } else if (MODE == 1) {
    int ms = wv >> 1, ntl = wv & 1;
    #pragma unroll
    for (int r = 0; r < 4; ++r) {
      int node = nb + ms*16 + rb + r;
      int ch = ntl*16 + col;
      DST[(size_t)(ch*3 + c)*NN + node] += accA[r];
    }
  } else {
    if (wv < 2) {
      #pragma unroll
      for (int r = 0; r < 4; ++r) {
        int node = nb + wv*16 + rb + r;
        DST[(size_t)col*NN + node] = accA[r];
      }
    }
  }
}

// ================= final bilinear + LDS-binned graph pool =================
__global__ __launch_bounds__(256) void k_fin2(
    const float* __restrict__ wl, const int* __restrict__ batch,
    const float* __restrict__ X16, float* __restrict__ out) {
  __shared__ float bins[NG];
  int t = threadIdx.x;
  for (int i = t; i < NG; i += 256) bins[i] = 0.f;
  __syncthreads();
  int n = blockIdx.x*256 + t;
  if (n < NN) {
    float x16[16];
    #pragma unroll
    for (int k = 0; k < 16; ++k) x16[k] = siluf(X16[(size_t)k*NN + n]);
    float o = 0.f;
    #pragma unroll
    for (int i = 0; i < 16; ++i) {
      float xi = x16[i];
      #pragma unroll
      for (int j = 0; j < 16; ++j) o += xi*x16[j]*wl[i*16+j];
    }
    o *= (1.0f/16.0f)*0.05f;  // /16 then /sqrt(400)
    atomicAdd(&bins[batch[n]], o);
  }
  __syncthreads();
  for (int i = t; i < NG; i += 256)
    if (bins[i] != 0.f) atomicAdd(&out[i], bins[i]);
}

extern "C" void kernel_launch(void* const* d_in, const int* in_sizes, int n_in,
                              void* d_out, int out_size, void* d_ws, size_t ws_size,
                              hipStream_t stream) {
  const float* pos     = (const float*)d_in[0];
  const int*   atype   = (const int*)d_in[1];
  const int*   esrc    = (const int*)d_in[2];
  const int*   edst    = (const int*)d_in[3];
  const int*   batch   = (const int*)d_in[4];
  const float* embed   = (const float*)d_in[5];
  const float* w_tp0   = (const float*)d_in[6];
  const float* tpss    = (const float*)d_in[7];
  const float* tpvv    = (const float*)d_in[8];
  const float* tpsv    = (const float*)d_in[9];
  const float* tpvs    = (const float*)d_in[10];
  const float* pen_ss  = (const float*)d_in[11];
  const float* pen_vv  = (const float*)d_in[12];
  const float* w_last  = (const float*)d_in[13];
  const float* sc0     = (const float*)d_in[14];
  const float* lin1_0  = (const float*)d_in[15];
  const float* fc0_w1  = (const float*)d_in[16];
  const float* fc0_w2  = (const float*)d_in[17];
  const float* lin2_0s = (const float*)d_in[18];
  const float* lin2_0v = (const float*)d_in[19];
  const float* sc_s    = (const float*)d_in[20];
  const float* sc_v    = (const float*)d_in[21];
  const float* lin1_s  = (const float*)d_in[22];
  const float* lin1_v  = (const float*)d_in[23];
  const float* fc_w1   = (const float*)d_in[24];
  const float* fc_w2   = (const float*)d_in[25];
  const float* lin2_s  = (const float*)d_in[26];
  const float* lin2_v  = (const float*)d_in[27];

  float* ws = (float*)d_ws;
  float* out = (float*)d_out;

  size_t o = 0;
  float* EA_S = ws + o; o += NE;
  float* EA_V = ws + o; o += 3*(size_t)NE;
  float* BAS  = ws + o; o += 8*(size_t)NE;
  float* W1T  = ws + o; o += 1536;
  float* SC   = ws + o; o += 96*(size_t)NN;
  float* SCV  = ws + o; o += 96*(size_t)NN;
  float* LSB  = ws + o; o += 64*(size_t)NN;   // node-major; layer0 uses first 8*NN as [n][8]
  float* LVB  = ws + o; o += 96*(size_t)NN;   // node-major
  float* AG   = ws + o; o += 384*(size_t)NN;  // node-major
  float* AG0  = ws + o; o += 32*(size_t)NN;   // node-major
  float* SB   = ws + o; o += 64*(size_t)NN;
  float* VB   = ws + o; o += 96*(size_t)NN;
  float* X16  = ws + o; o += 16*(size_t)NN;
  int* ESRC_S = (int*)(ws + o); o += NE;
  int* PERM   = (int*)(ws + o); o += NE;
  int* DEG    = (int*)(ws + o); o += NN;
  int* ROWS   = (int*)(ws + o); o += NN + 1;
  int* CURSOR = (int*)(ws + o); o += NN;
  // packed TP weights (bf16 hi/lo, fragment order)
  unsigned short* PWS = (unsigned short*)(ws + o); o += 999424;  // 1,998,848 ushorts
  unsigned short* WSh[2] = { PWS,            PWS + 655360 };
  unsigned short* WSl[2] = { PWS + 327680,   PWS + 983040 };
  unsigned short* WVh[2] = { PWS + 1310720,  PWS + 1572864 };
  unsigned short* WVl[2] = { PWS + 1441792,  PWS + 1703936 };
  unsigned short* WPh    =   PWS + 1835008;
  unsigned short* WPl    =   PWS + 1916928;
  // packed radial MLP2 weights (64x192 per layer, bf16 hi/lo)
  unsigned short* PRW = (unsigned short*)(ws + o); o += 24576;   // 49,152 ushorts
  unsigned short* WRh[2] = { PRW,           PRW + 24576 };
  unsigned short* WRl[2] = { PRW + 12288,   PRW + 36864 };
  float* RW   = ws + o;

  size_t availF = (ws_size/4 > o) ? (ws_size/4 - o) : 0;
  size_t capL = (availF/192) & ~(size_t)255;
  int cap  = (int)(capL < (size_t)NE ? capL : (size_t)NE);
  if (cap < 1024) cap = 1024;
  size_t cap0L = (availF/16) & ~(size_t)255;
  int cap0 = (int)(cap0L < (size_t)NE ? cap0L : (size_t)NE);
  if (cap0 < 1024) cap0 = 1024;

  const int nbE = NE/256;        // 1250
  const int nbN = (NN+255)/256;  // 79
  const int nbG = NN*64/256;     // 5000 (wave per dst)
  const int nbG0 = NN*8/256;     // 625
  const int nbM = NN/32;         // 625 (mfma node tiles)

  hipMemsetAsync(out, 0, NG*sizeof(float), stream);
  // ---- CSR (once per call, shared by all 3 conv layers) ----
  hipMemsetAsync(DEG, 0, NN*sizeof(int), stream);
  k_hist<<<nbE,256,0,stream>>>(edst, DEG);
  k_scan<<<1,256,0,stream>>>(DEG, ROWS, CURSOR);
  k_scatter<<<nbE,256,0,stream>>>(edst, CURSOR, PERM);
  k_geom<<<nbE,256,0,stream>>>(pos, esrc, edst, PERM, ESRC_S, EA_S, EA_V, BAS);
  k_prep<<<1,256,0,stream>>>(fc0_w1, fc_w1, W1T);
  // ---- pack TP + radial weights (scales folded) ----
  for (int L = 0; L < 2; ++L) {
    k_packw<<<1280,256,0,stream>>>(tpss + (size_t)L*262144, tpvv + (size_t)L*65536,
                                   WSh[L], WSl[L], 5120, 64, 4096,
                                   0.1f*A_S_, 0.1f*A_S_*INV_SQRT3);
    k_packw<<<512,256,0,stream>>>(tpsv + (size_t)L*65536, tpvs + (size_t)L*65536,
                                  WVh[L], WVl[L], 4096, 32, 2048,
                                  0.1f*A_V_, 0.1f*A_V_);
    k_packr<<<48,256,0,stream>>>(fc_w2 + (size_t)L*12288, WRh[L], WRl[L]);
  }
  k_packw<<<320,256,0,stream>>>(pen_ss, pen_vv, WPh, WPl, 5120, 16, 4096,
                                A_S_, A_S_*INV_SQRT3);
  k_node0<<<nbN,256,0,stream>>>(atype, embed, w_tp0, sc0, lin1_0, SC, LSB);

  // ---- layer 0 conv ----
  hipMemsetAsync(AG0, 0, 32*(size_t)NN*sizeof(float), stream);
  for (int pLo = 0; pLo < NE; pLo += cap0) {
    int pHi = pLo + cap0 < NE ? pLo + cap0 : NE;
    int nb = (pHi - pLo + 255)/256;
    k_radial0<<<nb,256,0,stream>>>(BAS, EA_S, W1T, fc0_w2, RW, pLo, pHi, cap0);
    k_gather0<<<nbG0,256,0,stream>>>(ROWS, ESRC_S, EA_V, RW, LSB, AG0, pLo, pHi, cap0);
  }
  k_upd0<<<nbN,256,0,stream>>>(lin2_0s, lin2_0v, SC, SCV, AG0, SB, VB);

  // ---- layers 1,2 ----
  for (int L = 0; L < 2; ++L) {
    k_pre<<<nbN,256,0,stream>>>(sc_s + L*64*96, sc_v + L*32*32,
                                lin1_s + L*64*64, lin1_v + L*32*32,
                                SB, VB, SC, SCV, LSB, LVB);
    hipMemsetAsync(AG, 0, 384*(size_t)NN*sizeof(float), stream);
    for (int pLo = 0; pLo < NE; pLo += cap) {
      int pHi = pLo + cap < NE ? pLo + cap : NE;
      int nb32 = (pHi - pLo + 31)/32;
      k_radialg<<<nb32,256,0,stream>>>(BAS, EA_S, W1T + 512 + L*512, WRh[L], WRl[L],
                                       RW, pLo, pHi, cap);
      k_gather<<<nbG,256,0,stream>>>(ROWS, ESRC_S, EA_S, EA_V, RW, LSB, LVB, AG, pLo, pHi, cap);
    }
    k_upd<<<nbN,256,0,stream>>>(lin2_s + L*96*96, lin2_v + L*96*32, SC, SCV, AG);
    // MFMA self tensor product (residual)
    k_tpg<0><<<nbM,256,0,stream>>>(WSh[L], WSl[L], SC, SCV, SB);
    k_tpg<1><<<dim3(nbM,3),256,0,stream>>>(WVh[L], WVl[L], SC, SCV, VB);
  }
  k_tpg<2><<<nbM,256,0,stream>>>(WPh, WPl, SB, VB, X16);
  k_fin2<<<nbN,256,0,stream>>>(w_last, batch, X16, out);
}